// Round 1
// baseline (271.924 us; speedup 1.0000x reference)
//
#include <hip/hip_runtime.h>
#include <hip/hip_bf16.h>

// Binarized-weight 3x3 conv as implicit GEMM:
//   out[n,o,h,w] = sum_{c,kh,kw} sign(W[o,c,kh,kw]) * x[n,c,h+kh-1,w+kw-1]
// GEMM: D[o][p] = sum_k Wmat[o][k] * B[k][p],  k = (kh*3+kw)*128 + c.
// R3: single gemm block covers ALL 256 o (8 waves, 512 thr) so each B
// window is staged once (was twice). A and B double-buffered in LDS with
// one-step-ahead prefetch (T3 2-phase): glds for step s+1 issued BEFORE
// step s's MFMAs, so the barrier's vmcnt(0) drain waits on loads that had
// a full MFMA phase (~1.2k cyc) to land. 36 steps of K=32 (cc64 x kh x
// sub32 x kw), 32 MFMA/step/wave. LDS 100 KB -> 1 block/CU, pipeline
// (not TLP) hides latency, per m201 precedent.

typedef short bf16x8 __attribute__((ext_vector_type(8)));
typedef float f32x4 __attribute__((ext_vector_type(4)));

#define XT_ELEMS (32 * 66 * 66 * 128)
#define XT_BYTES (XT_ELEMS * 2)

__device__ __forceinline__ void glds16(const void* g, const void* l) {
    __builtin_amdgcn_global_load_lds(
        (const __attribute__((address_space(1))) void*)g,
        (__attribute__((address_space(3))) void*)l, 16, 0, 0);
}

// weight OIHW fp32 -> Wmat[o][j][c] = sign(w[o][c][j]) as bf16, j = kh*3+kw
__global__ void prep_w_kernel(const float* __restrict__ w,
                              __hip_bfloat16* __restrict__ wm) {
    int tid = blockIdx.x * 256 + threadIdx.x;   // 294912 total, exact grid
    int o = tid / 1152;
    int r = tid - o * 1152;
    int j = r >> 7;
    int c = r & 127;
    float v = w[o * 1152 + c * 9 + j];
    float s = (v > 0.f) ? 1.f : ((v < 0.f) ? -1.f : 0.f);
    wm[tid] = __float2bfloat16(s);
}

// x NCHW fp32 -> x_t[n][h+1][w+1][c] bf16 (66x66 spatial, zero halo).
// Coalesced both ways via LDS bounce; halo zeroing folded in (no memset).
__global__ void transpose_x_kernel(const float* __restrict__ x,
                                   __hip_bfloat16* __restrict__ xt) {
    __shared__ short tl[64 * 130];   // stride 130: +65 banks/row -> 2-way max
    const int t = threadIdx.x;
    const int n = blockIdx.x >> 6;
    const int h = blockIdx.x & 63;
    const float* xp = x + (size_t)n * 524288 + h * 64;
    // phase 1: lanes span w -> 256 B contiguous per wave-load
    for (int i = t; i < 8192; i += 256) {
        int w = i & 63, c = i >> 6;
        tl[w * 130 + c] = (short)__bfloat16_as_ushort(__float2bfloat16(xp[c * 4096 + w]));
    }
    // halo zeroing (disjoint addresses; no barrier needed vs phase 2)
    uint* xtn = (uint*)(xt + (size_t)n * 66 * 66 * 128);
    {
        int row = h + 1;
        if (t < 64)       xtn[(row * 66 + 0) * 64 + t] = 0u;        // col 0
        else if (t < 128) xtn[(row * 66 + 65) * 64 + (t - 64)] = 0u; // col 65
    }
    if (h == 0)  for (int i = t; i < 66 * 64; i += 256) xtn[i] = 0u;                  // row 0
    if (h == 63) for (int i = t; i < 66 * 64; i += 256) xtn[65 * 66 * 64 + i] = 0u;   // row 65
    __syncthreads();
    // phase 2: lanes span c (uint = 2 shorts) -> 256 B contiguous stores
    uint* xo = (uint*)(xt + ((size_t)(n * 66 + h + 1) * 66 + 1) * 128);
    for (int i = t; i < 4096; i += 256) {
        int c2 = i & 63;
        int w = i >> 6;
        xo[w * 64 + c2] = *(const uint*)(tl + w * 130 + c2 * 2);
    }
}

// Block: 256 o x 256 px (4 out rows of one n). 8 waves, each 64o x 128px.
// LDS: As[2][256 o][32 c] 32 KB dbuf, Bw[2][4x66 cells][64 c] 67.6 KB dbuf.
// 16B segs XOR-swizzled: A seg' = q^(o&3) (4 segs/row), B seg' = q^(cell&7)
// (8 segs/cell) -> all ds_read_b128 optimal (8 lanes/bank-slot).
// Step s = (cc64, kh, sub32, kw); prefetch A every step, B every 6 steps.
__global__ __launch_bounds__(512, 2) void gemm_kernel(
    const __hip_bfloat16* __restrict__ xt,
    const __hip_bfloat16* __restrict__ wm,
    float* __restrict__ out) {
    __shared__ short As[2][256 * 32];    // 2 x 16384 B
    __shared__ short Bw[2][264 * 64];    // 2 x 33792 B

    const int t = threadIdx.x;
    const int lane = t & 63;
    const int wv = t >> 6;              // 0..7
    const int l15 = lane & 15;
    const int quad = lane >> 4;

    const int bid = blockIdx.x;                      // 0..511
    const int px_blk = (bid & 7) * 64 + (bid >> 3);  // XCD-chunked swizzle (512%8==0)
    const int n = px_blk >> 4;
    const int h0 = (px_blk & 15) << 2;

    const int wo = (wv >> 1) * 64;      // wave o origin: 0/64/128/192
    const int wpr = (wv & 1) * 2;       // wave px-row origin: 0 or 2

    const short* wmS = (const short*)wm;
    const short* xtS = (const short*)xt + (size_t)(n * 66 + h0) * 66 * 128;

    f32x4 acc[4][8] = {};   // [o frag][px frag]

    // --- stage A chunk: 256 o x 32 c for (cc, j). 1024 segs = 16 issues.
    auto stageA = [&](int buf, int cc, int j) {
        const short* src = wmS + j * 128 + cc;
#pragma unroll
        for (int i = 0; i < 2; ++i) {
            int g = i * 8 + wv;          // 0..15
            int l = g * 64 + lane;       // seg id 0..1023
            int o = l >> 2, q = l & 3;
            glds16(src + o * 1152 + ((q ^ (o & 3)) * 8), &As[buf][g * 512]);
        }
    };
    // --- stage B window: rows (h0+kh..h0+kh+3) x 66 cols x 64 c.
    // 2112 segs = 33 issues (wave 0 takes 5, others 4).
    auto stageB = [&](int buf, int cc, int kh) {
        const short* src = xtS + kh * (66 * 128) + cc;
#pragma unroll
        for (int i = 0; i < 5; ++i) {
            int g = i * 8 + wv;          // 0..39
            if (g < 33) {
                int l = g * 64 + lane;
                int cell = l >> 3, q = l & 7;
                glds16(src + cell * 128 + ((q ^ (cell & 7)) * 8), &Bw[buf][g * 512]);
            }
        }
    };

    // prologue: stage step 0 into buffer 0
    stageB(0, 0, 0);
    stageA(0, 0, 0);
    __syncthreads();

    int Ab = 0, Bb = 0;
    for (int s = 0; s < 36; ++s) {
        const int s1 = s + 1;
        // prefetch step s+1 into the other buffers (issued BEFORE compute)
        if (s1 < 36) {
            const int cc64_1 = (s1 >= 18) ? 64 : 0;
            const int r1 = s1 % 18;
            const int kh1 = r1 / 6;
            const int sub1 = (r1 % 6) / 3;
            const int kw1 = r1 % 3;
            if (s1 % 6 == 0) stageB(Bb ^ 1, cc64_1, kh1);
            stageA(Ab ^ 1, cc64_1 + sub1 * 32, kh1 * 3 + kw1);
        }
        // compute step s from current buffers
        {
            const int r = s % 18;
            const int sub = (r % 6) / 3;
            const int kw = r % 3;
            const short* A_ = As[Ab];
            const short* B_ = Bw[Bb];
            bf16x8 a[4], b[8];
#pragma unroll
            for (int i = 0; i < 4; ++i) {
                int o = wo + i * 16 + l15;
                a[i] = *(const bf16x8*)(A_ + o * 32 + ((quad ^ (o & 3)) * 8));
            }
#pragma unroll
            for (int i = 0; i < 8; ++i) {
                int cell = (wpr + (i >> 2)) * 66 + (i & 3) * 16 + l15 + kw;
                int seg = (sub * 4 + quad) ^ (cell & 7);
                b[i] = *(const bf16x8*)(B_ + cell * 64 + seg * 8);
            }
#pragma unroll
            for (int i = 0; i < 4; ++i)
#pragma unroll
                for (int jj = 0; jj < 8; ++jj)
                    acc[i][jj] = __builtin_amdgcn_mfma_f32_16x16x32_bf16(
                        a[i], b[jj], acc[i][jj], 0, 0, 0);
        }
        __syncthreads();   // drains prefetch (issued a full MFMA phase ago)
        Ab ^= 1;
        if (s1 % 6 == 0) Bb ^= 1;
    }

    // Epilogue: C/D layout col=lane&15 (px), row=quad*4+reg (o)
    const int Pbase = px_blk * 256 + (wv & 1) * 128;
#pragma unroll
    for (int i = 0; i < 4; ++i) {
#pragma unroll
        for (int jj = 0; jj < 8; ++jj) {
            const int P = Pbase + jj * 16 + l15;
            const int hw = P & 4095;
            float* op = out + (size_t)n * 1048576 + hw;
#pragma unroll
            for (int r = 0; r < 4; ++r) {
                const int o = wo + i * 16 + quad * 4 + r;
                op[(size_t)o * 4096] = acc[i][jj][r];
            }
        }
    }
}

extern "C" void kernel_launch(void* const* d_in, const int* in_sizes, int n_in,
                              void* d_out, int out_size, void* d_ws, size_t ws_size,
                              hipStream_t stream) {
    const float* x = (const float*)d_in[0];
    const float* w = (const float*)d_in[1];
    float* out = (float*)d_out;
    __hip_bfloat16* xt = (__hip_bfloat16*)d_ws;
    __hip_bfloat16* wm = (__hip_bfloat16*)((char*)d_ws + XT_BYTES);

    prep_w_kernel<<<1152, 256, 0, stream>>>(w, wm);
    transpose_x_kernel<<<2048, 256, 0, stream>>>(x, xt);
    gemm_kernel<<<512, 512, 0, stream>>>(xt, wm, out);
}